// Round 10
// baseline (1867.539 us; speedup 1.0000x reference)
//
#include <hip/hip_runtime.h>
#include <math.h>

#define HH 128
#define WW 128
#define CIN 512
#define NPIX 16384
#define NPRE 6000
#define NPOST 300

// workspace offsets (floats; LOG region is doubles at even float offsets)
#define WS_WT     0ull                        // 2359296 floats (f32 wt2[(c*9+k)][perm m])
#define WS_LIST   2359296ull                  // 16384 ints (active pixel list)
#define WS_NACT   2375680ull                  // 1 int
#define WS_LOG    4718592ull                  // 16384*12 doubles = 393216 floats
#define WS_FG32   5111808ull                  // 16384
#define WS_ASCALE 5128192ull                  // 16384
#define WS_ASSIGN 5144576ull                  // 16384 (int)
#define WS_ROI    5160960ull                  // 16384*4
#define WS_SC32   5226496ull                  // 16384
#define WS_CAND   5242880ull                  // 6000*4
#define WS_TOPS   5266880ull                  // 6000

// d_out offsets (floats), concatenated tuple in return order
#define O_LOCS   0
#define O_ROIS   65536
#define O_RIDX   66736
#define O_ANCHOR 67036
#define O_CLS    132572
#define O_COS    247260
#define O_RSC    263644
#define O_OLD    263944

typedef double d4 __attribute__((ext_vector_type(4)));

__device__ __forceinline__ float exp32(float x) { return (float)exp((double)x); }
__device__ __forceinline__ float sqrt32(float x) { return (float)sqrt((double)x); }

__global__ __launch_bounds__(1024) void zero_kernel(double* __restrict__ p, int n) {
  int i = blockIdx.x * 1024 + threadIdx.x;
  if (i < n) p[i] = 0.0;
}

// weight transpose+permute: w[m][c][k] (f32) -> wt2[(c*9+k)][g*64 + (m%16)*4 + m/16]
// so that lane(col,kk) of a wave on group g reads its 4 nf B-values as one float4.
__global__ __launch_bounds__(256) void wt_kernel(const float* __restrict__ w,
                                                 float* __restrict__ wt2) {
  __shared__ float t[64][65];
  int ck0 = blockIdx.x * 64;
  int m0  = blockIdx.y * 64;
  int j  = threadIdx.x & 63;
  int i0 = threadIdx.x >> 6;
#pragma unroll
  for (int ii = 0; ii < 16; ++ii) {
    int i = i0 + ii * 4;
    t[i][j] = w[(size_t)(m0 + i) * 4608 + ck0 + j];
  }
  __syncthreads();
  int jp = ((j & 15) << 2) | (j >> 4);   // permuted m position within 64-group
#pragma unroll
  for (int ii = 0; ii < 16; ++ii) {
    int jj = i0 + ii * 4;
    wt2[(size_t)(ck0 + jj) * 512 + m0 + jp] = t[j][jj];
  }
}

// ------- compacted active-pixel list, deterministic row-major order ----------
__global__ __launch_bounds__(1024) void alist_kernel(const int* __restrict__ mask,
                                                     int* __restrict__ list,
                                                     int* __restrict__ nact) {
  __shared__ int sc[1024];
  int tid = threadIdx.x;
  int base = tid << 4;
  int m[16];
  int cnt = 0;
#pragma unroll
  for (int i = 0; i < 16; ++i) {
    m[i] = mask[base + i];
    cnt += (m[i] != 0);
  }
  sc[tid] = cnt;
  __syncthreads();
  for (int off = 1; off < 1024; off <<= 1) {
    int v = 0;
    if (tid >= off) v = sc[tid - off];
    __syncthreads();
    sc[tid] += v;
    __syncthreads();
  }
  int pos = sc[tid] - cnt;
#pragma unroll
  for (int i = 0; i < 16; ++i)
    if (m[i] != 0) list[pos++] = base + i;
  if (tid == 1023) nact[0] = sc[1023];
}

// ------- implicit-GEMM conv via fp64 MFMA 16x16x4 + fused heads --------------
// Block = ONE 16-pixel tile x ALL 512 outch (8 waves of 64). Per 8-channel
// K-step the block stages A = [8ch][9tap][16pix] into LDS ONCE (24 gather
// instructions vs 144 in the per-group scheme), double-buffered one full step
// ahead -> gather latency hides under the 4608-cy MFMA burst via the LDS
// handoff. Each wave ds_reads A (2-way bank aliasing = free) and keeps its
// coalesced B float4 loads. A values, accumulation order, epilogue identical
// to R9 (invalid taps stored as 0.0). Runtime-balanced XCD swizzle at tile
// granularity: XCD k owns contiguous tiles (~4.7MB x-slab ~= its L2).
// D layout probed at runtime (2 identity MFMAs).
__global__ __launch_bounds__(512, 2) void conv_mfma_kernel(
    const float* __restrict__ x, const float* __restrict__ wt2,
    const float* __restrict__ bias, const float* __restrict__ loc_w,
    const float* __restrict__ cls_w, const float* __restrict__ cos_w,
    const int* __restrict__ list, const int* __restrict__ nact,
    double* __restrict__ logits) {
  __shared__ float rlds[2][1152];   // [buf][cc*144 + j*16 + pix], 9216 B
  __shared__ int offs_s[144];       // [j*16 + pix], -1 = invalid tap
  int tid = threadIdx.x;
  int lane = tid & 63;
  int wv = tid >> 6;                // wave 0..7 -> outch group
  int n = nact[0];
  int ntile = (n + 15) >> 4;        // active 16-pixel tiles
  int lin = blockIdx.x;
  int xcd = lin & 7;
  int slot = lin >> 3;
  int wpx = (ntile + 7) >> 3;       // tiles per XCD (contiguous range)
  int tile = xcd * wpx + slot;
  if (slot >= wpx || tile >= ntile) return;   // block-uniform exit
  int m0 = wv << 6;
  int col = lane & 15;
  int kk = lane >> 4;

  // tap-offset table for this tile (all waves share it)
  if (tid < 144) {
    int j = tid >> 4, pix = tid & 15;
    int sp = tile * 16 + pix;
    int p = (sp < n) ? list[sp] : -1;
    int off = -1;
    if (p >= 0) {
      int py = p >> 7, px = p & 127;
      int yy = py + j / 3 - 1, xx = px + j % 3 - 1;
      if (yy >= 0 && yy < HH && xx >= 0 && xx < WW) off = yy * WW + xx;
    }
    offs_s[tid] = off;
  }

  // --- probe the D layout: rowmap[r], colmap[r] per lane register ---
  d4 zz = (d4){0.0, 0.0, 0.0, 0.0};
  double pa1 = (kk == 0) ? (double)col : 0.0;   // A[m][0] = m
  double pb1 = (kk == 0) ? 1.0 : 0.0;           // B[0][n] = 1
  d4 rp = __builtin_amdgcn_mfma_f64_16x16x4f64(pa1, pb1, zz, 0, 0, 0);
  double pa2 = (kk == 0) ? 1.0 : 0.0;           // A[m][0] = 1
  double pb2 = (kk == 0) ? (double)col : 0.0;   // B[0][n] = n
  d4 cp = __builtin_amdgcn_mfma_f64_16x16x4f64(pa2, pb2, zz, 0, 0, 0);
  int rowmap[4], colmap[4];
#pragma unroll
  for (int r = 0; r < 4; ++r) {
    rowmap[r] = (int)rp[r];
    colmap[r] = (int)cp[r];
  }
  __syncthreads();

  // stage c0=0 into buf 0
#pragma unroll
  for (int base = 0; base < 1152; base += 512) {
    int idx = base + tid;
    if (idx < 1152) {
      int cc = idx / 144;
      int rem = idx - cc * 144;
      int off = offs_s[rem];
      float v = 0.f;
      if (off >= 0) v = x[(size_t)cc * NPIX + off];
      rlds[0][idx] = v;
    }
  }
  __syncthreads();

  d4 acc[4];
#pragma unroll
  for (int nf = 0; nf < 4; ++nf) acc[nf] = (d4){0.0, 0.0, 0.0, 0.0};

  const float* wk = wt2 + (size_t)(kk * 9) * 512 + m0 + (col << 2);

  int buf = 0;
  for (int c0 = 0; c0 < CIN; c0 += 8) {
    // stage next K-step into the other buffer (loads get a full MFMA burst
    // to land; barrier at loop end publishes them)
    if (c0 + 8 < CIN) {
      const float* xs = x + (size_t)(c0 + 8) * NPIX;
      float* dst = rlds[buf ^ 1];
#pragma unroll
      for (int base = 0; base < 1152; base += 512) {
        int idx = base + tid;
        if (idx < 1152) {
          int cc = idx / 144;
          int rem = idx - cc * 144;
          int off = offs_s[rem];
          float v = 0.f;
          if (off >= 0) v = xs[(size_t)cc * NPIX + off];
          dst[idx] = v;
        }
      }
    }
    // compute current buffer: 2 channel-quads x 9 taps x 4 frags = 72 MFMAs
    const float* src = rlds[buf];
    const float* wc = wk + (size_t)c0 * 4608;   // c0*9*512
#pragma unroll
    for (int q = 0; q < 2; ++q) {
      float4 bv[9];
#pragma unroll
      for (int j = 0; j < 9; ++j)
        bv[j] = *(const float4*)(wc + q * 4 * 4608 + j * 512);
#pragma unroll
      for (int j = 0; j < 9; ++j) {
        double a = (double)src[(q * 4 + kk) * 144 + j * 16 + col];
        acc[0] = __builtin_amdgcn_mfma_f64_16x16x4f64(a, (double)bv[j].x, acc[0], 0, 0, 0);
        acc[1] = __builtin_amdgcn_mfma_f64_16x16x4f64(a, (double)bv[j].y, acc[1], 0, 0, 0);
        acc[2] = __builtin_amdgcn_mfma_f64_16x16x4f64(a, (double)bv[j].z, acc[2], 0, 0, 0);
        acc[3] = __builtin_amdgcn_mfma_f64_16x16x4f64(a, (double)bv[j].w, acc[3], 0, 0, 0);
      }
    }
    __syncthreads();
    buf ^= 1;
  }

  // Layout-independent epilogue: for reg jj this lane's acc element is
  // D[rowmap[jj]][colmap[jj]] of the 16x64 tile. Apply bias/relu per true col,
  // dot with head weights per true col, reduce the 16 lanes of each kk-group
  // (they jointly cover one full row), write to pixel tile*16+rowmap[jj].
#pragma unroll
  for (int jj = 0; jj < 4; ++jj) {
    int cm = colmap[jj];
    float hvj[4];
#pragma unroll
    for (int nf = 0; nf < 4; ++nf) {
      float bb = bias[m0 + nf * 16 + cm];
      hvj[nf] = fmaxf(__fadd_rn((float)acc[nf][jj], bb), 0.f);
    }
    int s2 = tile * 16 + rowmap[jj];
    bool wr = (col == 0) && (s2 < n);
    int pix = wr ? list[s2] : 0;
#pragma unroll
    for (int r = 0; r < 12; ++r) {
      double t = 0.0;
#pragma unroll
      for (int nf = 0; nf < 4; ++nf) {
        int oc = m0 + nf * 16 + cm;
        float wh = (r < 4) ? loc_w[r * 512 + oc]
                           : (r < 11) ? cls_w[(r - 4) * 512 + oc] : cos_w[oc];
        t += (double)hvj[nf] * (double)wh;
      }
#pragma unroll
      for (int o = 8; o; o >>= 1) t += __shfl_xor(t, o, 16);
      if (wr) atomicAdd(&logits[(size_t)pix * 12 + r], t);
    }
  }
}

// ------- finalize per pixel: f64 softmax/argmax/sigmoid, cast to f32 ----------
__global__ __launch_bounds__(256) void finalize_kernel(
    const double* __restrict__ logits, const float* __restrict__ loc_b,
    const float* __restrict__ cls_b, const float* __restrict__ cos_b,
    float* __restrict__ out, float* __restrict__ fg32,
    float* __restrict__ ascale, int* __restrict__ assign) {
  int p = blockIdx.x * 256 + threadIdx.x;
  const double* lg = &logits[(size_t)p * 12];
#pragma unroll
  for (int o = 0; o < 4; ++o)
    out[O_LOCS + p * 4 + o] = (float)(lg[o] + (double)loc_b[o]);
  double cl[7];
#pragma unroll
  for (int i = 0; i < 7; ++i) {
    cl[i] = lg[4 + i] + (double)cls_b[i];
    out[O_CLS + p * 7 + i] = (float)cl[i];
  }
  double z = lg[11] + (double)cos_b[0];
  double sig = 1.0 / (1.0 + exp(-z));
  out[O_COS + p] = (float)sig;
  double pm = cl[0];
  int ai = 0;
#pragma unroll
  for (int i = 1; i < 7; ++i)
    if (cl[i] > pm) { pm = cl[i]; ai = i; }
  double mx = cl[0];
#pragma unroll
  for (int i = 1; i < 7; ++i) mx = fmax(mx, cl[i]);
  double S = 0.0;
#pragma unroll
  for (int i = 0; i < 7; ++i) S += exp(cl[i] - mx);
  double p0 = exp(cl[0] - mx) / S;
  fg32[p] = (float)(1.0 - p0);
  assign[p] = ai;
  const float BS[7] = {16.f, 9.f, 14.f, 21.f, 33.f, 54.f, 93.f};
  ascale[p] = BS[ai];
}

// -------- anchors, loc2bbox, clip, validity, scores — fp32 op-for-op ----------
__global__ __launch_bounds__(256) void roi_kernel(
    float* __restrict__ out, const float* __restrict__ fg32,
    const float* __restrict__ ascale, const int* __restrict__ assign,
    const int* __restrict__ img_h, const int* __restrict__ img_w,
    float* __restrict__ roi, float* __restrict__ scores32) {
  int p = blockIdx.x * 256 + threadIdx.x;
  float a0 = out[O_COS + 0];
  if (a0 == 0.0f) a0 = __fadd_rn(a0, 1e-5f);
  float t1 = __fmul_rn(a0, a0);
  float t2 = __fdiv_rn(1.0f, t1);
  float t3 = __fsub_rn(t2, 1.0f);
  float anchor_h = __fmul_rn(ascale[0], sqrt32(t3));
  float anchor_w = ascale[p];
  float ay = __fadd_rn((float)(p >> 7) * 8.0f, 4.0f);
  float ax = __fadd_rn((float)(p & 127) * 8.0f, 4.0f);
  float A0 = __fsub_rn(ay, __fmul_rn(0.5f, anchor_h));
  float A1 = __fsub_rn(ax, __fmul_rn(0.5f, anchor_w));
  float A2 = __fadd_rn(ay, __fmul_rn(0.5f, anchor_h));
  float A3 = __fadd_rn(ax, __fmul_rn(0.5f, anchor_w));
  *(float4*)&out[O_ANCHOR + p * 4] = make_float4(A0, A1, A2, A3);
  float hA = __fsub_rn(A2, A0), wA = __fsub_rn(A3, A1);
  float cy = __fadd_rn(A0, __fmul_rn(0.5f, hA));
  float cx = __fadd_rn(A1, __fmul_rn(0.5f, wA));
  float l0 = out[O_LOCS + p * 4 + 0], l1 = out[O_LOCS + p * 4 + 1];
  float l2 = out[O_LOCS + p * 4 + 2], l3 = out[O_LOCS + p * 4 + 3];
  float ncy = __fadd_rn(__fmul_rn(l0, hA), cy);
  float ncx = __fadd_rn(__fmul_rn(l1, wA), cx);
  float nh = __fmul_rn(exp32(l2), hA);
  float nw = __fmul_rn(exp32(l3), wA);
  float b0 = __fsub_rn(ncy, __fmul_rn(0.5f, nh));
  float b1 = __fsub_rn(ncx, __fmul_rn(0.5f, nw));
  float b2 = __fadd_rn(ncy, __fmul_rn(0.5f, nh));
  float b3 = __fadd_rn(ncx, __fmul_rn(0.5f, nw));
  float IH = (float)img_h[0], IW = (float)img_w[0];
  b0 = fminf(fmaxf(b0, 0.f), IH);
  b1 = fminf(fmaxf(b1, 0.f), IW);
  b2 = fminf(fmaxf(b2, 0.f), IH);
  b3 = fminf(fmaxf(b3, 0.f), IW);
  *(float4*)&roi[p * 4] = make_float4(b0, b1, b2, b3);
  float hs = __fsub_rn(b2, b0), wd = __fsub_rn(b3, b1);
  bool valid = (assign[p] > 0) && (hs >= 16.f) && (wd >= 16.f);
  scores32[p] = valid ? fg32[p] : -INFINITY;
}

// ----- stable descending sort (bitonic) on fp32 score bits + index asc -------
__global__ __launch_bounds__(1024) void sort_kernel(
    const float* __restrict__ scores32, const float* __restrict__ roi,
    float* __restrict__ out, float* __restrict__ cand, float* __restrict__ tops) {
  __shared__ unsigned long long keys[16384];
  int tid = threadIdx.x;
  for (int i = tid; i < 16384; i += 1024) {
    unsigned u = __float_as_uint(scores32[i]);
    u = (u & 0x80000000u) ? ~u : (u | 0x80000000u);
    keys[i] = ((unsigned long long)(~u) << 32) | (unsigned)i;
  }
  __syncthreads();
  for (int k = 2; k <= 16384; k <<= 1) {
    for (int j = k >> 1; j > 0; j >>= 1) {
      for (int i = tid; i < 16384; i += 1024) {
        int l = i ^ j;
        if (l > i) {
          unsigned long long a = keys[i], b = keys[l];
          bool up = ((i & k) == 0);
          if ((a > b) == up) { keys[i] = b; keys[l] = a; }
        }
      }
      __syncthreads();
    }
  }
  for (int t = tid; t < NPRE; t += 1024) {
    int idx = (int)(keys[t] & 0x3FFFull);
    float s = scores32[idx];
    float4 b = make_float4(0.f, 0.f, 0.f, 0.f);
    if (isfinite(s)) b = *(const float4*)&roi[idx * 4];
    ((float4*)(out + O_OLD))[t] = b;
    ((float4*)cand)[t] = b;
    tops[t] = s;
  }
}

// --- sequential NMS (round-5 proven version): boxes in immutable LDS, live
// --- scores in registers, fused suppress+argmax pass, 2 barriers/iter --------
__global__ __launch_bounds__(1024) void nms_kernel(const float* __restrict__ cand,
                                                   const float* __restrict__ tops,
                                                   float* __restrict__ out) {
  __shared__ float sy0[NPRE], sx0[NPRE], sy1[NPRE], sx1[NPRE], sar[NPRE], ssc[NPRE];
  __shared__ unsigned long long red[16];
  __shared__ unsigned long long bestk_s;
  int tid = threadIdx.x;
  float rsc[6];
#pragma unroll
  for (int j = 0; j < 6; ++j) {
    int i = tid + j * 1024;
    if (i < NPRE) {
      float4 b = ((const float4*)cand)[i];
      float s = tops[i];
      float ar = __fmul_rn(__fsub_rn(b.z, b.x), __fsub_rn(b.w, b.y));
      sy0[i] = b.x; sx0[i] = b.y; sy1[i] = b.z; sx1[i] = b.w;
      sar[i] = ar; ssc[i] = s;
      rsc[j] = s;
    } else {
      rsc[j] = -INFINITY;
    }
  }
  __syncthreads();
  int lane = tid & 63, wid = tid >> 6;
  float py0 = 0.f, px0 = 0.f, py1 = 0.f, px1 = 0.f, par = 0.f;
  bool havepick = false;
  for (int k = 0; k < NPOST; ++k) {
    unsigned long long best = 0;
#pragma unroll
    for (int j = 0; j < 6; ++j) {
      int i = tid + j * 1024;
      if (i < NPRE) {
        float s = rsc[j];
        if (havepick && s != -INFINITY) {
          float yy0 = fmaxf(sy0[i], py0), xx0 = fmaxf(sx0[i], px0);
          float yy1 = fminf(sy1[i], py1), xx1 = fminf(sx1[i], px1);
          float inter = __fmul_rn(fmaxf(__fsub_rn(yy1, yy0), 0.f),
                                  fmaxf(__fsub_rn(xx1, xx0), 0.f));
          float den = __fadd_rn(__fsub_rn(__fadd_rn(sar[i], par), inter), 1e-9f);
          float iou = __fdiv_rn(inter, den);
          if (iou > 0.7f) { rsc[j] = -INFINITY; s = -INFINITY; }
        }
        unsigned u = __float_as_uint(s);
        u = (u & 0x80000000u) ? ~u : (u | 0x80000000u);
        unsigned long long key =
            ((unsigned long long)u << 32) | (unsigned)(NPRE - i);
        if (key > best) best = key;
      }
    }
#pragma unroll
    for (int off = 32; off; off >>= 1) {
      unsigned long long o = __shfl_xor(best, off, 64);
      if (o > best) best = o;
    }
    if (lane == 0) red[wid] = best;
    __syncthreads();
    if (tid == 0) {
      unsigned long long b = red[0];
      for (int w2 = 1; w2 < 16; ++w2)
        if (red[w2] > b) b = red[w2];
      bestk_s = b;
    }
    __syncthreads();
    unsigned long long b = bestk_s;
    int i = NPRE - (int)(b & 0xFFFFFFFFull);
    bool valid = (unsigned)(b >> 32) > 0x007FFFFFu;
    py0 = sy0[i]; px0 = sx0[i]; py1 = sy1[i]; px1 = sx1[i]; par = sar[i];
    havepick = true;
    if (tid == 0) {
      if (valid) {
        out[O_ROIS + k * 4 + 0] = py0;
        out[O_ROIS + k * 4 + 1] = px0;
        out[O_ROIS + k * 4 + 2] = py1;
        out[O_ROIS + k * 4 + 3] = px1;
        out[O_RSC + k] = ssc[i];
      } else {
        out[O_ROIS + k * 4 + 0] = 0.f;
        out[O_ROIS + k * 4 + 1] = 0.f;
        out[O_ROIS + k * 4 + 2] = 0.f;
        out[O_ROIS + k * 4 + 3] = 0.f;
        out[O_RSC + k] = 0.f;
      }
    }
  }
  for (int t = tid; t < NPOST; t += 1024) out[O_RIDX + t] = 0.f;
}

extern "C" void kernel_launch(void* const* d_in, const int* in_sizes, int n_in,
                              void* d_out, int out_size, void* d_ws, size_t ws_size,
                              hipStream_t stream) {
  (void)in_sizes; (void)n_in; (void)out_size; (void)ws_size;
  const float* x      = (const float*)d_in[0];
  const int*   skel   = (const int*)d_in[1];
  const float* conv_w = (const float*)d_in[2];
  const float* conv_b = (const float*)d_in[3];
  const float* loc_w  = (const float*)d_in[4];
  const float* loc_b  = (const float*)d_in[5];
  const float* cls_w  = (const float*)d_in[6];
  const float* cls_b  = (const float*)d_in[7];
  const float* cos_w  = (const float*)d_in[8];
  const float* cos_b  = (const float*)d_in[9];
  const int*   img_h  = (const int*)d_in[10];
  const int*   img_w  = (const int*)d_in[11];
  float* out = (float*)d_out;
  float* ws  = (float*)d_ws;

  float*  wt2      = ws + WS_WT;
  int*    list     = (int*)(ws + WS_LIST);
  int*    nact     = (int*)(ws + WS_NACT);
  double* logits   = (double*)(ws + WS_LOG);
  float*  fg32     = ws + WS_FG32;
  float*  ascale   = ws + WS_ASCALE;
  int*    assign   = (int*)(ws + WS_ASSIGN);
  float*  roi      = ws + WS_ROI;
  float*  scores32 = ws + WS_SC32;
  float*  cand     = ws + WS_CAND;
  float*  tops     = ws + WS_TOPS;

  hipLaunchKernelGGL(zero_kernel, dim3(192), dim3(1024), 0, stream, logits, NPIX * 12);
  hipLaunchKernelGGL(wt_kernel, dim3(72, 8), dim3(256), 0, stream, conv_w, wt2);
  hipLaunchKernelGGL(alist_kernel, dim3(1), dim3(1024), 0, stream, skel, list, nact);
  hipLaunchKernelGGL(conv_mfma_kernel, dim3(1024), dim3(512), 0, stream, x, wt2,
                     conv_b, loc_w, cls_w, cos_w, list, nact, logits);
  hipLaunchKernelGGL(finalize_kernel, dim3(64), dim3(256), 0, stream, logits, loc_b,
                     cls_b, cos_b, out, fg32, ascale, assign);
  hipLaunchKernelGGL(roi_kernel, dim3(64), dim3(256), 0, stream, out, fg32, ascale,
                     assign, img_h, img_w, roi, scores32);
  hipLaunchKernelGGL(sort_kernel, dim3(1), dim3(1024), 0, stream, scores32, roi, out,
                     cand, tops);
  hipLaunchKernelGGL(nms_kernel, dim3(1), dim3(1024), 0, stream, cand, tops, out);
}

// Round 11
// 1686.296 us; speedup vs baseline: 1.1075x; 1.1075x over previous
//
#include <hip/hip_runtime.h>
#include <math.h>

#define HH 128
#define WW 128
#define CIN 512
#define NPIX 16384
#define NPRE 6000
#define NPOST 300

// workspace offsets (floats; LOG region is doubles at even float offsets)
#define WS_WT     0ull                        // 2359296 floats (f32 wt2[(c*9+k)][perm m])
#define WS_LIST   2359296ull                  // 16384 ints (active pixel list)
#define WS_NACT   2375680ull                  // 1 int
#define WS_LOG    4718592ull                  // 16384*12 doubles = 393216 floats
#define WS_FG32   5111808ull                  // 16384
#define WS_ASCALE 5128192ull                  // 16384
#define WS_ASSIGN 5144576ull                  // 16384 (int)
#define WS_ROI    5160960ull                  // 16384*4
#define WS_SC32   5226496ull                  // 16384
#define WS_CAND   5242880ull                  // 6000*4
#define WS_TOPS   5266880ull                  // 6000

// d_out offsets (floats), concatenated tuple in return order
#define O_LOCS   0
#define O_ROIS   65536
#define O_RIDX   66736
#define O_ANCHOR 67036
#define O_CLS    132572
#define O_COS    247260
#define O_RSC    263644
#define O_OLD    263944

typedef double d4 __attribute__((ext_vector_type(4)));

__device__ __forceinline__ float exp32(float x) { return (float)exp((double)x); }
__device__ __forceinline__ float sqrt32(float x) { return (float)sqrt((double)x); }

__global__ __launch_bounds__(1024) void zero_kernel(double* __restrict__ p, int n) {
  int i = blockIdx.x * 1024 + threadIdx.x;
  if (i < n) p[i] = 0.0;
}

// weight transpose+permute: w[m][c][k] (f32) -> wt2[(c*9+k)][g*64 + (m%16)*4 + m/16]
// so that lane(col,kk) of a wave on group g reads its 4 nf B-values as one float4.
__global__ __launch_bounds__(256) void wt_kernel(const float* __restrict__ w,
                                                 float* __restrict__ wt2) {
  __shared__ float t[64][65];
  int ck0 = blockIdx.x * 64;
  int m0  = blockIdx.y * 64;
  int j  = threadIdx.x & 63;
  int i0 = threadIdx.x >> 6;
#pragma unroll
  for (int ii = 0; ii < 16; ++ii) {
    int i = i0 + ii * 4;
    t[i][j] = w[(size_t)(m0 + i) * 4608 + ck0 + j];
  }
  __syncthreads();
  int jp = ((j & 15) << 2) | (j >> 4);   // permuted m position within 64-group
#pragma unroll
  for (int ii = 0; ii < 16; ++ii) {
    int jj = i0 + ii * 4;
    wt2[(size_t)(ck0 + jj) * 512 + m0 + jp] = t[j][jj];
  }
}

// ------- compacted active-pixel list, deterministic row-major order ----------
__global__ __launch_bounds__(1024) void alist_kernel(const int* __restrict__ mask,
                                                     int* __restrict__ list,
                                                     int* __restrict__ nact) {
  __shared__ int sc[1024];
  int tid = threadIdx.x;
  int base = tid << 4;
  int m[16];
  int cnt = 0;
#pragma unroll
  for (int i = 0; i < 16; ++i) {
    m[i] = mask[base + i];
    cnt += (m[i] != 0);
  }
  sc[tid] = cnt;
  __syncthreads();
  for (int off = 1; off < 1024; off <<= 1) {
    int v = 0;
    if (tid >= off) v = sc[tid - off];
    __syncthreads();
    sc[tid] += v;
    __syncthreads();
  }
  int pos = sc[tid] - cnt;
#pragma unroll
  for (int i = 0; i < 16; ++i)
    if (m[i] != 0) list[pos++] = base + i;
  if (tid == 1023) nact[0] = sc[1023];
}

__device__ __forceinline__ void conv_comp4(const float* raws, const float4* bvs,
                                           const bool* valj, d4* acc) {
#pragma unroll
  for (int j = 0; j < 9; ++j) {
    float av = valj[j] ? raws[j] : 0.f;
    double a = (double)av;
    acc[0] = __builtin_amdgcn_mfma_f64_16x16x4f64(a, (double)bvs[j].x, acc[0], 0, 0, 0);
    acc[1] = __builtin_amdgcn_mfma_f64_16x16x4f64(a, (double)bvs[j].y, acc[1], 0, 0, 0);
    acc[2] = __builtin_amdgcn_mfma_f64_16x16x4f64(a, (double)bvs[j].z, acc[2], 0, 0, 0);
    acc[3] = __builtin_amdgcn_mfma_f64_16x16x4f64(a, (double)bvs[j].w, acc[3], 0, 0, 0);
  }
}

// ------- implicit-GEMM conv via fp64 MFMA 16x16x4 + fused heads --------------
// R9 exact structure (best measured: 918us, 57.6% MfmaUtil — plateau across
// 7 schedule variants). Runtime-balanced XCD swizzle, 72-MFMA batches.
__global__ __launch_bounds__(256, 2) void conv_mfma_kernel(
    const float* __restrict__ x, const float* __restrict__ wt2,
    const float* __restrict__ bias, const float* __restrict__ loc_w,
    const float* __restrict__ cls_w, const float* __restrict__ cos_w,
    const int* __restrict__ list, const int* __restrict__ nact,
    double* __restrict__ logits) {
  int tid = threadIdx.x;
  int lane = tid & 63;
  int wv = tid >> 6;                  // wave 0..3
  int n = nact[0];
  int ntg = (n + 63) >> 6;            // active tile-groups (4 x 16-pixel tiles)
  int total = ntg << 3;               // work items: tile-major (w = tg*8 + g)
  int lin = blockIdx.x;
  int xcd = lin & 7;
  int slot = lin >> 3;
  int wpx = (total + 7) >> 3;         // work items per XCD
  int w = xcd * wpx + slot;
  if (slot >= wpx || w >= total) return;   // block-uniform exit
  int tg = w >> 3;                    // tile-group (contiguous range per XCD)
  int m0 = (w & 7) << 6;              // outch group base
  int tile = tg * 4 + wv;             // 16-pixel tile
  if (tile * 16 >= n) return;         // tail: wave-uniform exit, no barriers
  int col = lane & 15;
  int kk = lane >> 4;

  // --- probe the D layout: rowmap[r], colmap[r] per lane register ---
  d4 zz = (d4){0.0, 0.0, 0.0, 0.0};
  double pa1 = (kk == 0) ? (double)col : 0.0;   // A[m][0] = m
  double pb1 = (kk == 0) ? 1.0 : 0.0;           // B[0][n] = 1
  d4 rp = __builtin_amdgcn_mfma_f64_16x16x4f64(pa1, pb1, zz, 0, 0, 0);
  double pa2 = (kk == 0) ? 1.0 : 0.0;           // A[m][0] = 1
  double pb2 = (kk == 0) ? (double)col : 0.0;   // B[0][n] = n
  d4 cp = __builtin_amdgcn_mfma_f64_16x16x4f64(pa2, pb2, zz, 0, 0, 0);
  int rowmap[4], colmap[4];
#pragma unroll
  for (int r = 0; r < 4; ++r) {
    rowmap[r] = (int)rp[r];
    colmap[r] = (int)cp[r];
  }

  int slotp = tile * 16 + col;        // A-row pixel for this lane
  int p = (slotp < n) ? list[slotp] : -1;
  bool pv = (p >= 0);
  int py = p >> 7, px = p & 127;

  // per-lane tap offsets + validity, hoisted out of the K loop
  int offj[9];
  bool valj[9];
#pragma unroll
  for (int j = 0; j < 9; ++j) {
    int dy = j / 3 - 1, dx = j % 3 - 1;
    int yy = py + dy, xx = px + dx;
    bool v = pv && (yy >= 0) && (yy < HH) && (xx >= 0) && (xx < WW);
    valj[j] = v;
    offj[j] = v ? (yy * WW + xx) : 0;
  }

  d4 acc[4];
#pragma unroll
  for (int nf = 0; nf < 4; ++nf) acc[nf] = (d4){0.0, 0.0, 0.0, 0.0};

  const float* xk = x + (size_t)kk * NPIX;
  const float* wk = wt2 + (size_t)(kk * 9) * 512 + m0 + (col << 2);

  for (int c0 = 0; c0 < CIN; c0 += 8) {
    const float* xc0 = xk + (size_t)c0 * NPIX;
    const float* xc1 = xc0 + (size_t)4 * NPIX;
    const float* wc0 = wk + (size_t)c0 * 4608;   // c0*9*512
    const float* wc1 = wc0 + 4 * 4608;
    // batch-issue all 36 loads (18 A dwords + 18 B dwordx4), then 72 MFMAs
    float raws[18];
    float4 bvs[18];
#pragma unroll
    for (int j = 0; j < 9; ++j) {
      raws[j] = xc0[offj[j]];
      raws[9 + j] = xc1[offj[j]];
      bvs[j] = *(const float4*)(wc0 + j * 512);
      bvs[9 + j] = *(const float4*)(wc1 + j * 512);
    }
    conv_comp4(raws, bvs, valj, acc);
    conv_comp4(raws + 9, bvs + 9, valj, acc);
  }

  // Layout-independent epilogue: for reg jj this lane's acc element is
  // D[rowmap[jj]][colmap[jj]] of the 16x64 tile.
#pragma unroll
  for (int jj = 0; jj < 4; ++jj) {
    int cm = colmap[jj];
    float hvj[4];
#pragma unroll
    for (int nf = 0; nf < 4; ++nf) {
      float bb = bias[m0 + nf * 16 + cm];
      hvj[nf] = fmaxf(__fadd_rn((float)acc[nf][jj], bb), 0.f);
    }
    int s2 = tile * 16 + rowmap[jj];
    bool wr = (col == 0) && (s2 < n);
    int pix = wr ? list[s2] : 0;
#pragma unroll
    for (int r = 0; r < 12; ++r) {
      double t = 0.0;
#pragma unroll
      for (int nf = 0; nf < 4; ++nf) {
        int oc = m0 + nf * 16 + cm;
        float wh = (r < 4) ? loc_w[r * 512 + oc]
                           : (r < 11) ? cls_w[(r - 4) * 512 + oc] : cos_w[oc];
        t += (double)hvj[nf] * (double)wh;
      }
#pragma unroll
      for (int o = 8; o; o >>= 1) t += __shfl_xor(t, o, 16);
      if (wr) atomicAdd(&logits[(size_t)pix * 12 + r], t);
    }
  }
}

// ------- finalize per pixel: f64 softmax/argmax/sigmoid, cast to f32 ----------
__global__ __launch_bounds__(256) void finalize_kernel(
    const double* __restrict__ logits, const float* __restrict__ loc_b,
    const float* __restrict__ cls_b, const float* __restrict__ cos_b,
    float* __restrict__ out, float* __restrict__ fg32,
    float* __restrict__ ascale, int* __restrict__ assign) {
  int p = blockIdx.x * 256 + threadIdx.x;
  const double* lg = &logits[(size_t)p * 12];
#pragma unroll
  for (int o = 0; o < 4; ++o)
    out[O_LOCS + p * 4 + o] = (float)(lg[o] + (double)loc_b[o]);
  double cl[7];
#pragma unroll
  for (int i = 0; i < 7; ++i) {
    cl[i] = lg[4 + i] + (double)cls_b[i];
    out[O_CLS + p * 7 + i] = (float)cl[i];
  }
  double z = lg[11] + (double)cos_b[0];
  double sig = 1.0 / (1.0 + exp(-z));
  out[O_COS + p] = (float)sig;
  double pm = cl[0];
  int ai = 0;
#pragma unroll
  for (int i = 1; i < 7; ++i)
    if (cl[i] > pm) { pm = cl[i]; ai = i; }
  double mx = cl[0];
#pragma unroll
  for (int i = 1; i < 7; ++i) mx = fmax(mx, cl[i]);
  double S = 0.0;
#pragma unroll
  for (int i = 0; i < 7; ++i) S += exp(cl[i] - mx);
  double p0 = exp(cl[0] - mx) / S;
  fg32[p] = (float)(1.0 - p0);
  assign[p] = ai;
  const float BS[7] = {16.f, 9.f, 14.f, 21.f, 33.f, 54.f, 93.f};
  ascale[p] = BS[ai];
}

// -------- anchors, loc2bbox, clip, validity, scores — fp32 op-for-op ----------
__global__ __launch_bounds__(256) void roi_kernel(
    float* __restrict__ out, const float* __restrict__ fg32,
    const float* __restrict__ ascale, const int* __restrict__ assign,
    const int* __restrict__ img_h, const int* __restrict__ img_w,
    float* __restrict__ roi, float* __restrict__ scores32) {
  int p = blockIdx.x * 256 + threadIdx.x;
  float a0 = out[O_COS + 0];
  if (a0 == 0.0f) a0 = __fadd_rn(a0, 1e-5f);
  float t1 = __fmul_rn(a0, a0);
  float t2 = __fdiv_rn(1.0f, t1);
  float t3 = __fsub_rn(t2, 1.0f);
  float anchor_h = __fmul_rn(ascale[0], sqrt32(t3));
  float anchor_w = ascale[p];
  float ay = __fadd_rn((float)(p >> 7) * 8.0f, 4.0f);
  float ax = __fadd_rn((float)(p & 127) * 8.0f, 4.0f);
  float A0 = __fsub_rn(ay, __fmul_rn(0.5f, anchor_h));
  float A1 = __fsub_rn(ax, __fmul_rn(0.5f, anchor_w));
  float A2 = __fadd_rn(ay, __fmul_rn(0.5f, anchor_h));
  float A3 = __fadd_rn(ax, __fmul_rn(0.5f, anchor_w));
  *(float4*)&out[O_ANCHOR + p * 4] = make_float4(A0, A1, A2, A3);
  float hA = __fsub_rn(A2, A0), wA = __fsub_rn(A3, A1);
  float cy = __fadd_rn(A0, __fmul_rn(0.5f, hA));
  float cx = __fadd_rn(A1, __fmul_rn(0.5f, wA));
  float l0 = out[O_LOCS + p * 4 + 0], l1 = out[O_LOCS + p * 4 + 1];
  float l2 = out[O_LOCS + p * 4 + 2], l3 = out[O_LOCS + p * 4 + 3];
  float ncy = __fadd_rn(__fmul_rn(l0, hA), cy);
  float ncx = __fadd_rn(__fmul_rn(l1, wA), cx);
  float nh = __fmul_rn(exp32(l2), hA);
  float nw = __fmul_rn(exp32(l3), wA);
  float b0 = __fsub_rn(ncy, __fmul_rn(0.5f, nh));
  float b1 = __fsub_rn(ncx, __fmul_rn(0.5f, nw));
  float b2 = __fadd_rn(ncy, __fmul_rn(0.5f, nh));
  float b3 = __fadd_rn(ncx, __fmul_rn(0.5f, nw));
  float IH = (float)img_h[0], IW = (float)img_w[0];
  b0 = fminf(fmaxf(b0, 0.f), IH);
  b1 = fminf(fmaxf(b1, 0.f), IW);
  b2 = fminf(fmaxf(b2, 0.f), IH);
  b3 = fminf(fmaxf(b3, 0.f), IW);
  *(float4*)&roi[p * 4] = make_float4(b0, b1, b2, b3);
  float hs = __fsub_rn(b2, b0), wd = __fsub_rn(b3, b1);
  bool valid = (assign[p] > 0) && (hs >= 16.f) && (wd >= 16.f);
  scores32[p] = valid ? fg32[p] : -INFINITY;
}

// ----- exact rank-selection replacing the single-block bitonic sort ----------
// Each of the 16384 elements counts keys strictly greater than its own
// (key = mapped score bits desc, index asc tie-break — identical order to the
// old stable sort). rank < 6000 scatters directly into cand/tops/old_rois.
// 64 blocks x 256 threads; LDS-tiled broadcast reads.
__global__ __launch_bounds__(256) void rank_kernel(
    const float* __restrict__ scores32, const float* __restrict__ roi,
    float* __restrict__ out, float* __restrict__ cand, float* __restrict__ tops) {
  __shared__ unsigned long long kt[2048];
  int tid = threadIdx.x;
  int i = blockIdx.x * 256 + tid;           // owned element
  unsigned u = __float_as_uint(scores32[i]);
  u = (u & 0x80000000u) ? ~u : (u | 0x80000000u);
  unsigned long long mykey = ((unsigned long long)u << 32) | (unsigned)(16383 - i);
  int rank = 0;
  for (int t0 = 0; t0 < 16384; t0 += 2048) {
    __syncthreads();
#pragma unroll
    for (int s = 0; s < 8; ++s) {
      int j = t0 + s * 256 + tid;
      unsigned uj = __float_as_uint(scores32[j]);
      uj = (uj & 0x80000000u) ? ~uj : (uj | 0x80000000u);
      kt[s * 256 + tid] = ((unsigned long long)uj << 32) | (unsigned)(16383 - j);
    }
    __syncthreads();
    for (int t = 0; t < 2048; ++t)
      rank += (kt[t] > mykey) ? 1 : 0;
  }
  if (rank < NPRE) {
    float s = scores32[i];
    float4 b = make_float4(0.f, 0.f, 0.f, 0.f);
    if (isfinite(s)) b = *(const float4*)&roi[i * 4];
    ((float4*)(out + O_OLD))[rank] = b;
    ((float4*)cand)[rank] = b;
    tops[rank] = s;
  }
}

// --- sequential NMS, find-first-live form. cand is sorted desc (stable), so
// --- ref's argmax over live scores == FIRST live element in array order.
// --- Per iter: windowed ballot find (no key build, no u64 shuffles, no serial
// --- tid0 scan) + suppress live elements. fp32 IoU op-for-op identical. ------
__global__ __launch_bounds__(1024) void nms_kernel(const float* __restrict__ cand,
                                                   const float* __restrict__ tops,
                                                   float* __restrict__ out) {
  __shared__ float sy0[NPRE], sx0[NPRE], sy1[NPRE], sx1[NPRE], sar[NPRE], ssc[NPRE];
  __shared__ unsigned char live[NPRE];
  __shared__ int red[16];
  int tid = threadIdx.x;
  int lane = tid & 63, wid = tid >> 6;
#pragma unroll
  for (int j = 0; j < 6; ++j) {
    int i = tid + j * 1024;
    if (i < NPRE) {
      float4 b = ((const float4*)cand)[i];
      sy0[i] = b.x; sx0[i] = b.y; sy1[i] = b.z; sx1[i] = b.w;
      sar[i] = __fmul_rn(__fsub_rn(b.z, b.x), __fsub_rn(b.w, b.y));
      ssc[i] = tops[i];
      live[i] = 1;
    }
  }
  __syncthreads();
  int front = 0;
  for (int k = 0; k < NPOST; ++k) {
    // find first live index >= front (1024-wide windows; loop is rare)
    int next = 0x7FFFFFFF;
    int sb = front;
    while (true) {
      int c = sb + tid;
      bool pred = (c < NPRE) && live[c];
      unsigned long long bal = __ballot(pred);
      int wc = bal ? (sb + (wid << 6) + (int)__builtin_ctzll(bal)) : 0x7FFFFFFF;
      if (lane == 0) red[wid] = wc;
      __syncthreads();
      next = red[0];
#pragma unroll
      for (int w2 = 1; w2 < 16; ++w2) next = min(next, red[w2]);
      if (next != 0x7FFFFFFF || sb + 1024 >= NPRE) break;
      sb += 1024;
      __syncthreads();   // protect red[] reuse across windows
    }
    bool valid = (next != 0x7FFFFFFF) && (ssc[next] != -INFINITY);
    float py0 = 0.f, px0 = 0.f, py1 = 0.f, px1 = 0.f, par = 0.f;
    if (valid) {
      py0 = sy0[next]; px0 = sx0[next]; py1 = sy1[next]; px1 = sx1[next];
      par = sar[next];
      front = next + 1;
    } else if (next == 0x7FFFFFFF) {
      front = NPRE;
    }  // else: front stays at the live -inf element (every later pick invalid)
    if (tid == 0) {
      if (valid) {
        out[O_ROIS + k * 4 + 0] = py0;
        out[O_ROIS + k * 4 + 1] = px0;
        out[O_ROIS + k * 4 + 2] = py1;
        out[O_ROIS + k * 4 + 3] = px1;
        out[O_RSC + k] = ssc[next];
        live[next] = 0;
      } else {
        out[O_ROIS + k * 4 + 0] = 0.f;
        out[O_ROIS + k * 4 + 1] = 0.f;
        out[O_ROIS + k * 4 + 2] = 0.f;
        out[O_ROIS + k * 4 + 3] = 0.f;
        out[O_RSC + k] = 0.f;
      }
    }
    if (valid) {
#pragma unroll
      for (int j = 0; j < 6; ++j) {
        int i = tid + j * 1024;
        if (i < NPRE && live[i]) {
          float yy0 = fmaxf(sy0[i], py0), xx0 = fmaxf(sx0[i], px0);
          float yy1 = fminf(sy1[i], py1), xx1 = fminf(sx1[i], px1);
          float inter = __fmul_rn(fmaxf(__fsub_rn(yy1, yy0), 0.f),
                                  fmaxf(__fsub_rn(xx1, xx0), 0.f));
          float den = __fadd_rn(__fsub_rn(__fadd_rn(sar[i], par), inter), 1e-9f);
          float iou = __fdiv_rn(inter, den);
          if (iou > 0.7f) live[i] = 0;
        }
      }
    }
    __syncthreads();   // publish live[] + protect red[] for next iteration
  }
  for (int t = tid; t < NPOST; t += 1024) out[O_RIDX + t] = 0.f;
}

extern "C" void kernel_launch(void* const* d_in, const int* in_sizes, int n_in,
                              void* d_out, int out_size, void* d_ws, size_t ws_size,
                              hipStream_t stream) {
  (void)in_sizes; (void)n_in; (void)out_size; (void)ws_size;
  const float* x      = (const float*)d_in[0];
  const int*   skel   = (const int*)d_in[1];
  const float* conv_w = (const float*)d_in[2];
  const float* conv_b = (const float*)d_in[3];
  const float* loc_w  = (const float*)d_in[4];
  const float* loc_b  = (const float*)d_in[5];
  const float* cls_w  = (const float*)d_in[6];
  const float* cls_b  = (const float*)d_in[7];
  const float* cos_w  = (const float*)d_in[8];
  const float* cos_b  = (const float*)d_in[9];
  const int*   img_h  = (const int*)d_in[10];
  const int*   img_w  = (const int*)d_in[11];
  float* out = (float*)d_out;
  float* ws  = (float*)d_ws;

  float*  wt2      = ws + WS_WT;
  int*    list     = (int*)(ws + WS_LIST);
  int*    nact     = (int*)(ws + WS_NACT);
  double* logits   = (double*)(ws + WS_LOG);
  float*  fg32     = ws + WS_FG32;
  float*  ascale   = ws + WS_ASCALE;
  int*    assign   = (int*)(ws + WS_ASSIGN);
  float*  roi      = ws + WS_ROI;
  float*  scores32 = ws + WS_SC32;
  float*  cand     = ws + WS_CAND;
  float*  tops     = ws + WS_TOPS;

  hipLaunchKernelGGL(zero_kernel, dim3(192), dim3(1024), 0, stream, logits, NPIX * 12);
  hipLaunchKernelGGL(wt_kernel, dim3(72, 8), dim3(256), 0, stream, conv_w, wt2);
  hipLaunchKernelGGL(alist_kernel, dim3(1), dim3(1024), 0, stream, skel, list, nact);
  hipLaunchKernelGGL(conv_mfma_kernel, dim3(2048), dim3(256), 0, stream, x, wt2,
                     conv_b, loc_w, cls_w, cos_w, list, nact, logits);
  hipLaunchKernelGGL(finalize_kernel, dim3(64), dim3(256), 0, stream, logits, loc_b,
                     cls_b, cos_b, out, fg32, ascale, assign);
  hipLaunchKernelGGL(roi_kernel, dim3(64), dim3(256), 0, stream, out, fg32, ascale,
                     assign, img_h, img_w, roi, scores32);
  hipLaunchKernelGGL(rank_kernel, dim3(64), dim3(256), 0, stream, scores32, roi, out,
                     cand, tops);
  hipLaunchKernelGGL(nms_kernel, dim3(1), dim3(1024), 0, stream, cand, tops, out);
}

// Round 12
// 1392.605 us; speedup vs baseline: 1.3410x; 1.2109x over previous
//
#include <hip/hip_runtime.h>
#include <math.h>

#define HH 128
#define WW 128
#define CIN 512
#define NPIX 16384
#define NPRE 6000
#define NPOST 300
#define NMW 94          // u64 words per mask row: ceil(6000/64)

// workspace offsets (floats; LOG region doubles, MASK region u64, 8B-aligned)
#define WS_WT     0ull                        // 2359296 floats (f32 wt2)
#define WS_LIST   2359296ull                  // 16384 ints
#define WS_NACT   2375680ull                  // 1 int
#define WS_MASK   2375684ull                  // 6000*94 u64 = 1128000 floats
#define WS_LOG    4718592ull                  // 16384*12 doubles
#define WS_FG32   5111808ull                  // 16384
#define WS_ASCALE 5128192ull                  // 16384
#define WS_ASSIGN 5144576ull                  // 16384 (int)
#define WS_ROI    5160960ull                  // 16384*4
#define WS_SC32   5226496ull                  // 16384
#define WS_CAND   5242880ull                  // 6000*4
#define WS_TOPS   5266880ull                  // 6000

// d_out offsets (floats), concatenated tuple in return order
#define O_LOCS   0
#define O_ROIS   65536
#define O_RIDX   66736
#define O_ANCHOR 67036
#define O_CLS    132572
#define O_COS    247260
#define O_RSC    263644
#define O_OLD    263944

typedef double d4 __attribute__((ext_vector_type(4)));

__device__ __forceinline__ float exp32(float x) { return (float)exp((double)x); }
__device__ __forceinline__ float sqrt32(float x) { return (float)sqrt((double)x); }

__global__ __launch_bounds__(1024) void zero_kernel(double* __restrict__ p, int n) {
  int i = blockIdx.x * 1024 + threadIdx.x;
  if (i < n) p[i] = 0.0;
}

// weight transpose+permute: w[m][c][k] (f32) -> wt2[(c*9+k)][g*64 + (m%16)*4 + m/16]
__global__ __launch_bounds__(256) void wt_kernel(const float* __restrict__ w,
                                                 float* __restrict__ wt2) {
  __shared__ float t[64][65];
  int ck0 = blockIdx.x * 64;
  int m0  = blockIdx.y * 64;
  int j  = threadIdx.x & 63;
  int i0 = threadIdx.x >> 6;
#pragma unroll
  for (int ii = 0; ii < 16; ++ii) {
    int i = i0 + ii * 4;
    t[i][j] = w[(size_t)(m0 + i) * 4608 + ck0 + j];
  }
  __syncthreads();
  int jp = ((j & 15) << 2) | (j >> 4);   // permuted m position within 64-group
#pragma unroll
  for (int ii = 0; ii < 16; ++ii) {
    int jj = i0 + ii * 4;
    wt2[(size_t)(ck0 + jj) * 512 + m0 + jp] = t[j][jj];
  }
}

// ------- compacted active-pixel list, deterministic row-major order ----------
__global__ __launch_bounds__(1024) void alist_kernel(const int* __restrict__ mask,
                                                     int* __restrict__ list,
                                                     int* __restrict__ nact) {
  __shared__ int sc[1024];
  int tid = threadIdx.x;
  int base = tid << 4;
  int m[16];
  int cnt = 0;
#pragma unroll
  for (int i = 0; i < 16; ++i) {
    m[i] = mask[base + i];
    cnt += (m[i] != 0);
  }
  sc[tid] = cnt;
  __syncthreads();
  for (int off = 1; off < 1024; off <<= 1) {
    int v = 0;
    if (tid >= off) v = sc[tid - off];
    __syncthreads();
    sc[tid] += v;
    __syncthreads();
  }
  int pos = sc[tid] - cnt;
#pragma unroll
  for (int i = 0; i < 16; ++i)
    if (m[i] != 0) list[pos++] = base + i;
  if (tid == 1023) nact[0] = sc[1023];
}

__device__ __forceinline__ void conv_comp4(const float* raws, const float4* bvs,
                                           const bool* valj, d4* acc) {
#pragma unroll
  for (int j = 0; j < 9; ++j) {
    float av = valj[j] ? raws[j] : 0.f;
    double a = (double)av;
    acc[0] = __builtin_amdgcn_mfma_f64_16x16x4f64(a, (double)bvs[j].x, acc[0], 0, 0, 0);
    acc[1] = __builtin_amdgcn_mfma_f64_16x16x4f64(a, (double)bvs[j].y, acc[1], 0, 0, 0);
    acc[2] = __builtin_amdgcn_mfma_f64_16x16x4f64(a, (double)bvs[j].z, acc[2], 0, 0, 0);
    acc[3] = __builtin_amdgcn_mfma_f64_16x16x4f64(a, (double)bvs[j].w, acc[3], 0, 0, 0);
  }
}

// ------- implicit-GEMM conv via fp64 MFMA 16x16x4 + fused heads --------------
// R9 exact structure (plateau: 918us, 57.6% MfmaUtil across 7 variants).
__global__ __launch_bounds__(256, 2) void conv_mfma_kernel(
    const float* __restrict__ x, const float* __restrict__ wt2,
    const float* __restrict__ bias, const float* __restrict__ loc_w,
    const float* __restrict__ cls_w, const float* __restrict__ cos_w,
    const int* __restrict__ list, const int* __restrict__ nact,
    double* __restrict__ logits) {
  int tid = threadIdx.x;
  int lane = tid & 63;
  int wv = tid >> 6;                  // wave 0..3
  int n = nact[0];
  int ntg = (n + 63) >> 6;            // active tile-groups (4 x 16-pixel tiles)
  int total = ntg << 3;               // work items: tile-major (w = tg*8 + g)
  int lin = blockIdx.x;
  int xcd = lin & 7;
  int slot = lin >> 3;
  int wpx = (total + 7) >> 3;         // work items per XCD
  int w = xcd * wpx + slot;
  if (slot >= wpx || w >= total) return;   // block-uniform exit
  int tg = w >> 3;                    // tile-group (contiguous range per XCD)
  int m0 = (w & 7) << 6;              // outch group base
  int tile = tg * 4 + wv;             // 16-pixel tile
  if (tile * 16 >= n) return;         // tail: wave-uniform exit, no barriers
  int col = lane & 15;
  int kk = lane >> 4;

  // --- probe the D layout: rowmap[r], colmap[r] per lane register ---
  d4 zz = (d4){0.0, 0.0, 0.0, 0.0};
  double pa1 = (kk == 0) ? (double)col : 0.0;   // A[m][0] = m
  double pb1 = (kk == 0) ? 1.0 : 0.0;           // B[0][n] = 1
  d4 rp = __builtin_amdgcn_mfma_f64_16x16x4f64(pa1, pb1, zz, 0, 0, 0);
  double pa2 = (kk == 0) ? 1.0 : 0.0;           // A[m][0] = 1
  double pb2 = (kk == 0) ? (double)col : 0.0;   // B[0][n] = n
  d4 cp = __builtin_amdgcn_mfma_f64_16x16x4f64(pa2, pb2, zz, 0, 0, 0);
  int rowmap[4], colmap[4];
#pragma unroll
  for (int r = 0; r < 4; ++r) {
    rowmap[r] = (int)rp[r];
    colmap[r] = (int)cp[r];
  }

  int slotp = tile * 16 + col;        // A-row pixel for this lane
  int p = (slotp < n) ? list[slotp] : -1;
  bool pv = (p >= 0);
  int py = p >> 7, px = p & 127;

  // per-lane tap offsets + validity, hoisted out of the K loop
  int offj[9];
  bool valj[9];
#pragma unroll
  for (int j = 0; j < 9; ++j) {
    int dy = j / 3 - 1, dx = j % 3 - 1;
    int yy = py + dy, xx = px + dx;
    bool v = pv && (yy >= 0) && (yy < HH) && (xx >= 0) && (xx < WW);
    valj[j] = v;
    offj[j] = v ? (yy * WW + xx) : 0;
  }

  d4 acc[4];
#pragma unroll
  for (int nf = 0; nf < 4; ++nf) acc[nf] = (d4){0.0, 0.0, 0.0, 0.0};

  const float* xk = x + (size_t)kk * NPIX;
  const float* wk = wt2 + (size_t)(kk * 9) * 512 + m0 + (col << 2);

  for (int c0 = 0; c0 < CIN; c0 += 8) {
    const float* xc0 = xk + (size_t)c0 * NPIX;
    const float* xc1 = xc0 + (size_t)4 * NPIX;
    const float* wc0 = wk + (size_t)c0 * 4608;   // c0*9*512
    const float* wc1 = wc0 + 4 * 4608;
    float raws[18];
    float4 bvs[18];
#pragma unroll
    for (int j = 0; j < 9; ++j) {
      raws[j] = xc0[offj[j]];
      raws[9 + j] = xc1[offj[j]];
      bvs[j] = *(const float4*)(wc0 + j * 512);
      bvs[9 + j] = *(const float4*)(wc1 + j * 512);
    }
    conv_comp4(raws, bvs, valj, acc);
    conv_comp4(raws + 9, bvs + 9, valj, acc);
  }

#pragma unroll
  for (int jj = 0; jj < 4; ++jj) {
    int cm = colmap[jj];
    float hvj[4];
#pragma unroll
    for (int nf = 0; nf < 4; ++nf) {
      float bb = bias[m0 + nf * 16 + cm];
      hvj[nf] = fmaxf(__fadd_rn((float)acc[nf][jj], bb), 0.f);
    }
    int s2 = tile * 16 + rowmap[jj];
    bool wr = (col == 0) && (s2 < n);
    int pix = wr ? list[s2] : 0;
#pragma unroll
    for (int r = 0; r < 12; ++r) {
      double t = 0.0;
#pragma unroll
      for (int nf = 0; nf < 4; ++nf) {
        int oc = m0 + nf * 16 + cm;
        float wh = (r < 4) ? loc_w[r * 512 + oc]
                           : (r < 11) ? cls_w[(r - 4) * 512 + oc] : cos_w[oc];
        t += (double)hvj[nf] * (double)wh;
      }
#pragma unroll
      for (int o = 8; o; o >>= 1) t += __shfl_xor(t, o, 16);
      if (wr) atomicAdd(&logits[(size_t)pix * 12 + r], t);
    }
  }
}

// ------- finalize per pixel: f64 softmax/argmax/sigmoid, cast to f32 ----------
__global__ __launch_bounds__(256) void finalize_kernel(
    const double* __restrict__ logits, const float* __restrict__ loc_b,
    const float* __restrict__ cls_b, const float* __restrict__ cos_b,
    float* __restrict__ out, float* __restrict__ fg32,
    float* __restrict__ ascale, int* __restrict__ assign) {
  int p = blockIdx.x * 256 + threadIdx.x;
  const double* lg = &logits[(size_t)p * 12];
#pragma unroll
  for (int o = 0; o < 4; ++o)
    out[O_LOCS + p * 4 + o] = (float)(lg[o] + (double)loc_b[o]);
  double cl[7];
#pragma unroll
  for (int i = 0; i < 7; ++i) {
    cl[i] = lg[4 + i] + (double)cls_b[i];
    out[O_CLS + p * 7 + i] = (float)cl[i];
  }
  double z = lg[11] + (double)cos_b[0];
  double sig = 1.0 / (1.0 + exp(-z));
  out[O_COS + p] = (float)sig;
  double pm = cl[0];
  int ai = 0;
#pragma unroll
  for (int i = 1; i < 7; ++i)
    if (cl[i] > pm) { pm = cl[i]; ai = i; }
  double mx = cl[0];
#pragma unroll
  for (int i = 1; i < 7; ++i) mx = fmax(mx, cl[i]);
  double S = 0.0;
#pragma unroll
  for (int i = 0; i < 7; ++i) S += exp(cl[i] - mx);
  double p0 = exp(cl[0] - mx) / S;
  fg32[p] = (float)(1.0 - p0);
  assign[p] = ai;
  const float BS[7] = {16.f, 9.f, 14.f, 21.f, 33.f, 54.f, 93.f};
  ascale[p] = BS[ai];
}

// -------- anchors, loc2bbox, clip, validity, scores — fp32 op-for-op ----------
__global__ __launch_bounds__(256) void roi_kernel(
    float* __restrict__ out, const float* __restrict__ fg32,
    const float* __restrict__ ascale, const int* __restrict__ assign,
    const int* __restrict__ img_h, const int* __restrict__ img_w,
    float* __restrict__ roi, float* __restrict__ scores32) {
  int p = blockIdx.x * 256 + threadIdx.x;
  float a0 = out[O_COS + 0];
  if (a0 == 0.0f) a0 = __fadd_rn(a0, 1e-5f);
  float t1 = __fmul_rn(a0, a0);
  float t2 = __fdiv_rn(1.0f, t1);
  float t3 = __fsub_rn(t2, 1.0f);
  float anchor_h = __fmul_rn(ascale[0], sqrt32(t3));
  float anchor_w = ascale[p];
  float ay = __fadd_rn((float)(p >> 7) * 8.0f, 4.0f);
  float ax = __fadd_rn((float)(p & 127) * 8.0f, 4.0f);
  float A0 = __fsub_rn(ay, __fmul_rn(0.5f, anchor_h));
  float A1 = __fsub_rn(ax, __fmul_rn(0.5f, anchor_w));
  float A2 = __fadd_rn(ay, __fmul_rn(0.5f, anchor_h));
  float A3 = __fadd_rn(ax, __fmul_rn(0.5f, anchor_w));
  *(float4*)&out[O_ANCHOR + p * 4] = make_float4(A0, A1, A2, A3);
  float hA = __fsub_rn(A2, A0), wA = __fsub_rn(A3, A1);
  float cy = __fadd_rn(A0, __fmul_rn(0.5f, hA));
  float cx = __fadd_rn(A1, __fmul_rn(0.5f, wA));
  float l0 = out[O_LOCS + p * 4 + 0], l1 = out[O_LOCS + p * 4 + 1];
  float l2 = out[O_LOCS + p * 4 + 2], l3 = out[O_LOCS + p * 4 + 3];
  float ncy = __fadd_rn(__fmul_rn(l0, hA), cy);
  float ncx = __fadd_rn(__fmul_rn(l1, wA), cx);
  float nh = __fmul_rn(exp32(l2), hA);
  float nw = __fmul_rn(exp32(l3), wA);
  float b0 = __fsub_rn(ncy, __fmul_rn(0.5f, nh));
  float b1 = __fsub_rn(ncx, __fmul_rn(0.5f, nw));
  float b2 = __fadd_rn(ncy, __fmul_rn(0.5f, nh));
  float b3 = __fadd_rn(ncx, __fmul_rn(0.5f, nw));
  float IH = (float)img_h[0], IW = (float)img_w[0];
  b0 = fminf(fmaxf(b0, 0.f), IH);
  b1 = fminf(fmaxf(b1, 0.f), IW);
  b2 = fminf(fmaxf(b2, 0.f), IH);
  b3 = fminf(fmaxf(b3, 0.f), IW);
  *(float4*)&roi[p * 4] = make_float4(b0, b1, b2, b3);
  float hs = __fsub_rn(b2, b0), wd = __fsub_rn(b3, b1);
  bool valid = (assign[p] > 0) && (hs >= 16.f) && (wd >= 16.f);
  scores32[p] = valid ? fg32[p] : -INFINITY;
}

// ----- exact rank-selection (same key order as the old stable sort) ----------
__global__ __launch_bounds__(256) void rank_kernel(
    const float* __restrict__ scores32, const float* __restrict__ roi,
    float* __restrict__ out, float* __restrict__ cand, float* __restrict__ tops) {
  __shared__ unsigned long long kt[2048];
  int tid = threadIdx.x;
  int i = blockIdx.x * 256 + tid;           // owned element
  unsigned u = __float_as_uint(scores32[i]);
  u = (u & 0x80000000u) ? ~u : (u | 0x80000000u);
  unsigned long long mykey = ((unsigned long long)u << 32) | (unsigned)(16383 - i);
  int rank = 0;
  for (int t0 = 0; t0 < 16384; t0 += 2048) {
    __syncthreads();
#pragma unroll
    for (int s = 0; s < 8; ++s) {
      int j = t0 + s * 256 + tid;
      unsigned uj = __float_as_uint(scores32[j]);
      uj = (uj & 0x80000000u) ? ~uj : (uj | 0x80000000u);
      kt[s * 256 + tid] = ((unsigned long long)uj << 32) | (unsigned)(16383 - j);
    }
    __syncthreads();
    for (int t = 0; t < 2048; ++t)
      rank += (kt[t] > mykey) ? 1 : 0;
  }
  if (rank < NPRE) {
    float s = scores32[i];
    float4 b = make_float4(0.f, 0.f, 0.f, 0.f);
    if (isfinite(s)) b = *(const float4*)&roi[i * 4];
    ((float4*)(out + O_OLD))[rank] = b;
    ((float4*)cand)[rank] = b;
    tops[rank] = s;
  }
}

// ----- NMS stage 1: whole-GPU pairwise suppression mask ----------------------
// mask[i][w] bit b: j = w*64+b, j>i, iou(i,j) > 0.7 (ref's exact fp32 op
// order: den = ((areas[j] + areas[i]) - inter) + 1e-9). grid (94 col-words,
// 94 row-blocks) x 64 threads; thread t owns row r = bj*64+t.
__global__ __launch_bounds__(64) void nms_mask_kernel(
    const float* __restrict__ cand, unsigned long long* __restrict__ mask) {
  __shared__ float cy0[64], cx0[64], cy1[64], cx1[64], car[64];
  int bw = blockIdx.x;   // column word
  int bj = blockIdx.y;   // row block
  int t = threadIdx.x;
  int c = bw * 64 + t;
  if (c < NPRE) {
    float4 b = ((const float4*)cand)[c];
    cy0[t] = b.x; cx0[t] = b.y; cy1[t] = b.z; cx1[t] = b.w;
    car[t] = __fmul_rn(__fsub_rn(b.z, b.x), __fsub_rn(b.w, b.y));
  } else {
    cy0[t] = 0.f; cx0[t] = 0.f; cy1[t] = 0.f; cx1[t] = 0.f; car[t] = 0.f;
  }
  __syncthreads();
  int r = bj * 64 + t;
  if (r >= NPRE) return;
  float4 rb = ((const float4*)cand)[r];
  float rar = __fmul_rn(__fsub_rn(rb.z, rb.x), __fsub_rn(rb.w, rb.y));
  unsigned long long bits = 0;
#pragma unroll 4
  for (int b = 0; b < 64; ++b) {
    int j = bw * 64 + b;
    float yy0 = fmaxf(cy0[b], rb.x), xx0 = fmaxf(cx0[b], rb.y);
    float yy1 = fminf(cy1[b], rb.z), xx1 = fminf(cx1[b], rb.w);
    float inter = __fmul_rn(fmaxf(__fsub_rn(yy1, yy0), 0.f),
                            fmaxf(__fsub_rn(xx1, xx0), 0.f));
    float den = __fadd_rn(__fsub_rn(__fadd_rn(car[b], rar), inter), 1e-9f);
    float iou = __fdiv_rn(inter, den);
    if (j > r && j < NPRE && iou > 0.7f)
      bits |= 1ull << b;
  }
  mask[(size_t)r * NMW + bw] = bits;
}

// ----- NMS stage 2: tiny serial reduce over the bitmask ----------------------
// cand sorted desc (stable) => greedy pick = first unremoved index. Per pick:
// find-first-zero-bit over remv[94] (shuffle-min), OR the pick's mask row
// (+ self bit folded in). First unremoved with -inf score, or none left =>
// all remaining picks invalid (ref: zero box suppresses nothing, never
// self-removes) => break and zero-fill.
__global__ __launch_bounds__(128) void nms_reduce_kernel(
    const float* __restrict__ cand, const float* __restrict__ tops,
    const unsigned long long* __restrict__ mask, float* __restrict__ out) {
  __shared__ unsigned long long remv[NMW];
  __shared__ int red2[2];
  int tid = threadIdx.x;
  int lane = tid & 63, wid = tid >> 6;
  if (tid < NMW) remv[tid] = 0ull;
  __syncthreads();
  int kdone = NPOST;
  for (int k = 0; k < NPOST; ++k) {
    int cnd = 0x7FFFFFFF;
    if (tid < NMW) {
      unsigned long long avail = ~remv[tid];
      if (tid == NMW - 1) avail &= (1ull << (NPRE - (NMW - 1) * 64)) - 1;
      if (avail) cnd = (tid << 6) + (int)__builtin_ctzll(avail);
    }
#pragma unroll
    for (int off = 32; off; off >>= 1) {
      int o = __shfl_xor(cnd, off, 64);
      cnd = min(cnd, o);
    }
    if (lane == 0) red2[wid] = cnd;
    __syncthreads();
    int pick = min(red2[0], red2[1]);
    bool valid = (pick != 0x7FFFFFFF) && (tops[pick] != -INFINITY);
    if (!valid) { kdone = k; break; }
    if (tid == 0) {
      float4 b = ((const float4*)cand)[pick];
      out[O_ROIS + k * 4 + 0] = b.x;
      out[O_ROIS + k * 4 + 1] = b.y;
      out[O_ROIS + k * 4 + 2] = b.z;
      out[O_ROIS + k * 4 + 3] = b.w;
      out[O_RSC + k] = tops[pick];
    }
    if (tid < NMW) {
      unsigned long long m = mask[(size_t)pick * NMW + tid];
      if (tid == (pick >> 6)) m |= 1ull << (pick & 63);
      remv[tid] |= m;
    }
    __syncthreads();
  }
  for (int t = kdone + tid; t < NPOST; t += 128) {
    out[O_ROIS + t * 4 + 0] = 0.f;
    out[O_ROIS + t * 4 + 1] = 0.f;
    out[O_ROIS + t * 4 + 2] = 0.f;
    out[O_ROIS + t * 4 + 3] = 0.f;
    out[O_RSC + t] = 0.f;
  }
  for (int t = tid; t < NPOST; t += 128) out[O_RIDX + t] = 0.f;
}

extern "C" void kernel_launch(void* const* d_in, const int* in_sizes, int n_in,
                              void* d_out, int out_size, void* d_ws, size_t ws_size,
                              hipStream_t stream) {
  (void)in_sizes; (void)n_in; (void)out_size; (void)ws_size;
  const float* x      = (const float*)d_in[0];
  const int*   skel   = (const int*)d_in[1];
  const float* conv_w = (const float*)d_in[2];
  const float* conv_b = (const float*)d_in[3];
  const float* loc_w  = (const float*)d_in[4];
  const float* loc_b  = (const float*)d_in[5];
  const float* cls_w  = (const float*)d_in[6];
  const float* cls_b  = (const float*)d_in[7];
  const float* cos_w  = (const float*)d_in[8];
  const float* cos_b  = (const float*)d_in[9];
  const int*   img_h  = (const int*)d_in[10];
  const int*   img_w  = (const int*)d_in[11];
  float* out = (float*)d_out;
  float* ws  = (float*)d_ws;

  float*  wt2      = ws + WS_WT;
  int*    list     = (int*)(ws + WS_LIST);
  int*    nact     = (int*)(ws + WS_NACT);
  unsigned long long* nmsmask = (unsigned long long*)(ws + WS_MASK);
  double* logits   = (double*)(ws + WS_LOG);
  float*  fg32     = ws + WS_FG32;
  float*  ascale   = ws + WS_ASCALE;
  int*    assign   = (int*)(ws + WS_ASSIGN);
  float*  roi      = ws + WS_ROI;
  float*  scores32 = ws + WS_SC32;
  float*  cand     = ws + WS_CAND;
  float*  tops     = ws + WS_TOPS;

  hipLaunchKernelGGL(zero_kernel, dim3(192), dim3(1024), 0, stream, logits, NPIX * 12);
  hipLaunchKernelGGL(wt_kernel, dim3(72, 8), dim3(256), 0, stream, conv_w, wt2);
  hipLaunchKernelGGL(alist_kernel, dim3(1), dim3(1024), 0, stream, skel, list, nact);
  hipLaunchKernelGGL(conv_mfma_kernel, dim3(2048), dim3(256), 0, stream, x, wt2,
                     conv_b, loc_w, cls_w, cos_w, list, nact, logits);
  hipLaunchKernelGGL(finalize_kernel, dim3(64), dim3(256), 0, stream, logits, loc_b,
                     cls_b, cos_b, out, fg32, ascale, assign);
  hipLaunchKernelGGL(roi_kernel, dim3(64), dim3(256), 0, stream, out, fg32, ascale,
                     assign, img_h, img_w, roi, scores32);
  hipLaunchKernelGGL(rank_kernel, dim3(64), dim3(256), 0, stream, scores32, roi, out,
                     cand, tops);
  hipLaunchKernelGGL(nms_mask_kernel, dim3(NMW, NMW), dim3(64), 0, stream, cand,
                     nmsmask);
  hipLaunchKernelGGL(nms_reduce_kernel, dim3(1), dim3(128), 0, stream, cand, tops,
                     nmsmask, out);
}